// Round 5
// baseline (2741.177 us; speedup 1.0000x reference)
//
#include <hip/hip_runtime.h>
#include <hip/hip_bf16.h>
#include <math.h>

#define D    256
#define BT   128     // chunk length == M tile
#define BN   64      // N tile per block (4 N-slices = 4 scan chains)
#define NSEG 32      // BT/4 segments per chunk

typedef unsigned short u16;
typedef __attribute__((ext_vector_type(8))) short short8;   // 8 bf16 = 4 VGPRs
typedef __attribute__((ext_vector_type(4))) float floatx4;  // MFMA C/D frag

__device__ __forceinline__ float b2f(u16 v) {
    union { unsigned u; float f; } x; x.u = ((unsigned)v) << 16; return x.f;
}
__device__ __forceinline__ u16 f2b(float f) {
    union { unsigned u; float f; } x; x.f = f;
    unsigned lsb = (x.u >> 16) & 1;
    x.u += 0x7fffu + lsb;                 // RNE
    return (u16)(x.u >> 16);
}
__device__ __forceinline__ float sigm(float x) {
    return __builtin_amdgcn_rcpf(1.0f + __expf(-x));
}
__device__ __forceinline__ float tanhfast(float x) {
    return 1.0f - 2.0f * __builtin_amdgcn_rcpf(__expf(2.0f * x) + 1.0f);
}
__device__ __forceinline__ void async16(const u16* g, u16* l) {
    __builtin_amdgcn_global_load_lds(
        (const __attribute__((address_space(1))) unsigned int*)g,
        (__attribute__((address_space(3))) unsigned int*)l, 16, 0, 0);
}

// ---------------------------------------------------------------------------
// weight transpose + bf16 cast: wt[combo][m][n][k] = bf16(W[k][n])
// ---------------------------------------------------------------------------
__global__ __launch_bounds__(256) void wtrans_kernel(
    const float* __restrict__ Wz_f, const float* __restrict__ Wh_f,
    const float* __restrict__ Wz_b, const float* __restrict__ Wh_b,
    u16* __restrict__ wt)
{
    int id = blockIdx.x * 256 + threadIdx.x;       // < 5*3*65536
    int combo = id / (3 * 65536);
    int rem   = id % (3 * 65536);
    int m = rem >> 16;
    int e = rem & 65535;
    int k = e >> 8, n = e & 255;
    int l   = combo < 3 ? combo : combo - 3;
    int dir = combo < 3 ? 0 : 1;
    float v;
    if (m == 0) {
        const float* Wz = dir ? Wz_b : Wz_f;
        v = Wz[((size_t)l * D + k) * D + n];
    } else {
        const float* Wh = dir ? Wh_b : Wh_f;
        int kk = (m == 2) ? (k + D) : k;
        v = Wh[((size_t)l * 2 * D + kk) * D + n];
    }
    wt[(size_t)combo * 3 * 65536 + (size_t)m * 65536 + (size_t)n * D + k] = f2b(v);
}

// ---------------------------------------------------------------------------
// Tier A prep: xb = bf16(x), q broadcast, xq = bf16(x*qbf)
// ---------------------------------------------------------------------------
__global__ __launch_bounds__(256) void prep0_kernel(
    const float* __restrict__ story, const float* __restrict__ question,
    u16* __restrict__ xb, u16* __restrict__ q, u16* __restrict__ xq)
{
    long id = (long)blockIdx.x * 256 + threadIdx.x;
    long row = id >> 5;
    int  d0  = (int)(id & 31) * 8;
    const float* xp = story + row * D + d0;
    float4 xa = *(const float4*)xp;
    float4 xc = *(const float4*)(xp + 4);
    float xv[8] = {xa.x, xa.y, xa.z, xa.w, xc.x, xc.y, xc.z, xc.w};
    short8 xs, qs, xqs;
    #pragma unroll
    for (int i = 0; i < 8; ++i) {
        u16 qb = f2b(question[d0 + i]);
        xs[i]  = (short)f2b(xv[i]);
        qs[i]  = (short)qb;
        xqs[i] = (short)f2b(xv[i] * b2f(qb));
    }
    long o = id * 8;
    *(short8*)(xb + o) = xs;
    *(short8*)(q  + o) = qs;
    *(short8*)(xq + o) = xqs;
}

// Tier B prep: q broadcast only
__global__ __launch_bounds__(256) void q_init_kernel(
    u16* __restrict__ q, const float* __restrict__ question, long total8)
{
    long id = (long)blockIdx.x * 256 + threadIdx.x;
    if (id < total8) {
        int d0 = (int)(id & 31) * 8;
        short8 v;
        #pragma unroll
        for (int i = 0; i < 8; ++i) v[i] = (short)f2b(question[d0 + i]);
        *(short8*)(q + id * 8) = v;
    }
}

// Tier A: xq = bf16(b2f(xb) * b2f(qnew))
__global__ __launch_bounds__(256) void xq_upd_kernel(
    const u16* __restrict__ xb, const u16* __restrict__ qn, u16* __restrict__ xq)
{
    long id = (long)blockIdx.x * 256 + threadIdx.x;
    long o  = id * 8;
    short8 xs = *(const short8*)(xb + o);
    short8 qs = *(const short8*)(qn + o);
    short8 r;
    #pragma unroll
    for (int i = 0; i < 8; ++i)
        r[i] = (short)f2b(b2f((u16)xs[i]) * b2f((u16)qs[i]));
    *(short8*)(xq + o) = r;
}

// ---------------------------------------------------------------------------
// LDS layouts (stage / epilogue overlay)
// ---------------------------------------------------------------------------
struct StageS {
    u16 ax [BT * 32]; u16 aq [BT * 32]; u16 axq[BT * 32];   // 8KB each
    u16 bz_[BN * 32]; u16 bx_[BN * 32]; u16 bq_[BN * 32];   // 4KB each
};
struct EpiS {
    float segA[NSEG][BN]; float segB[NSEG][BN]; float hseg[NSEG][BN];
    u16   hout[BT][BN];
};
union SharedU { StageS st; EpiS ep; };

// ===========================================================================
// TIER A: fused gates-GEMM + single-pass chunk scan (decoupled look-back).
// MODE 0: write h (bf16) to hout      (fwd, layers 0/1)
// MODE 1: accumulate h into hout      (bwd, layers 0/1)
// MODE 2: agg-only; last position per chain writes d_out  (fwd, layer 2)
// Scan chain = N-slice (chain owns its 64 channels exclusively).
// Position in chain = per-chain atomic ticket (arrival order -> no deadlock).
// Publication protocol: st 0=empty, 1=local (A,B), 2=inclusive prefix h.
// ===========================================================================
template<int FWD, int MODE>
__global__ __launch_bounds__(256) void qrn_fused(
    const u16* __restrict__ xbg, const u16* __restrict__ qg,
    const u16* __restrict__ xqg, const u16* __restrict__ wt,
    const float* __restrict__ bz, const float* __restrict__ bh,
    int* __restrict__ st, int* __restrict__ tickets,
    float* __restrict__ locA, float* __restrict__ locB, float* __restrict__ pre,
    u16* __restrict__ hout, float* __restrict__ outp)
{
    __shared__ SharedU sh;
    __shared__ int s_vid;
    const int tid  = threadIdx.x;
    const int NCH  = (int)(gridDim.x >> 2);
    const int chain = (int)blockIdx.x & 3;

    if (tid == 0) s_vid = atomicAdd(&tickets[chain], 1);
    __syncthreads();
    const int p  = s_vid;                       // position in processing order
    const int c  = FWD ? p : (NCH - 1 - p);     // chunk id
    const int n0 = chain * BN;
    const int t0 = c * BT;

    const int lane = tid & 63, w = tid >> 6;
    const int lr   = lane & 15, quad = lane >> 4;

    int offA[2], offB[4];
    #pragma unroll
    for (int rt = 0; rt < 2; ++rt) {
        int row = w * 32 + rt * 16 + lr;
        offA[rt] = row * 32 + (quad ^ ((row >> 1) & 3)) * 8;
    }
    #pragma unroll
    for (int ct = 0; ct < 4; ++ct) {
        int n = ct * 16 + lr;
        offB[ct] = n * 32 + (quad ^ ((n >> 1) & 3)) * 8;
    }

    floatx4 accz[2][4], acch[2][4];
    #pragma unroll
    for (int rt = 0; rt < 2; ++rt)
        #pragma unroll
        for (int ct = 0; ct < 4; ++ct) {
            accz[rt][ct] = (floatx4){0.f,0.f,0.f,0.f};
            acch[rt][ct] = (floatx4){0.f,0.f,0.f,0.f};
        }

    const u16* wz = wt;
    const u16* wx = wt + 65536;
    const u16* wq = wt + 131072;
    const int wbase = (tid & ~63) * 8;

    for (int k0 = 0; k0 < D; k0 += 32) {
        #pragma unroll
        for (int i = 0; i < 2; ++i) {
            int u = i * 256 + tid;
            int row = u >> 2, sl = u & 3;
            int gg = sl ^ ((row >> 1) & 3);
            size_t go = (size_t)(t0 + row) * D + k0 + gg * 8;
            int lb = (i * 256 + (tid & ~63)) * 8;
            async16(xbg + go, sh.st.ax  + lb);
            async16(qg  + go, sh.st.aq  + lb);
            async16(xqg + go, sh.st.axq + lb);
        }
        {
            int n = tid >> 2, sl = tid & 3;
            int gg = sl ^ ((n >> 1) & 3);
            size_t go = (size_t)(n0 + n) * D + k0 + gg * 8;
            async16(wz + go, sh.st.bz_ + wbase);
            async16(wx + go, sh.st.bx_ + wbase);
            async16(wq + go, sh.st.bq_ + wbase);
        }
        __syncthreads();

        short8 fx[2], fq[2], fxq[2];
        #pragma unroll
        for (int rt = 0; rt < 2; ++rt) {
            fx [rt] = *(const short8*)(sh.st.ax  + offA[rt]);
            fq [rt] = *(const short8*)(sh.st.aq  + offA[rt]);
            fxq[rt] = *(const short8*)(sh.st.axq + offA[rt]);
        }
        #pragma unroll
        for (int ct = 0; ct < 4; ++ct) {
            short8 vz = *(const short8*)(sh.st.bz_ + offB[ct]);
            short8 vx = *(const short8*)(sh.st.bx_ + offB[ct]);
            short8 vq = *(const short8*)(sh.st.bq_ + offB[ct]);
            #pragma unroll
            for (int rt = 0; rt < 2; ++rt) {
                accz[rt][ct] = __builtin_amdgcn_mfma_f32_16x16x32_bf16(fxq[rt], vz, accz[rt][ct], 0, 0, 0);
                acch[rt][ct] = __builtin_amdgcn_mfma_f32_16x16x32_bf16(fx [rt], vx, acch[rt][ct], 0, 0, 0);
                acch[rt][ct] = __builtin_amdgcn_mfma_f32_16x16x32_bf16(fq [rt], vq, acch[rt][ct], 0, 0, 0);
            }
        }
        __syncthreads();
    }

    // ---- gate epilogue (C/D: col = lr, rows = quad*4 + r)
    float av[2][4][4], bv[2][4][4];
    #pragma unroll
    for (int ct = 0; ct < 4; ++ct) {
        int n = n0 + ct * 16 + lr;
        float bzn = bz[n], bhn = bh[n];
        #pragma unroll
        for (int rt = 0; rt < 2; ++rt)
            #pragma unroll
            for (int r = 0; r < 4; ++r) {
                float z  = sigm(accz[rt][ct][r] + bzn);
                float ht = tanhfast(acch[rt][ct][r] + bhn);
                av[rt][ct][r] = 1.0f - z;
                bv[rt][ct][r] = z * ht;
            }
    }

    // ---- per-lane 4-step segment aggregates
    #pragma unroll
    for (int rt = 0; rt < 2; ++rt)
        #pragma unroll
        for (int ct = 0; ct < 4; ++ct) {
            float A = 1.f, B = 0.f;
            if (FWD) {
                #pragma unroll
                for (int r = 0; r < 4; ++r) { A = av[rt][ct][r] * A; B = fmaf(av[rt][ct][r], B, bv[rt][ct][r]); }
            } else {
                #pragma unroll
                for (int r = 3; r >= 0; --r) { A = av[rt][ct][r] * A; B = fmaf(av[rt][ct][r], B, bv[rt][ct][r]); }
            }
            int seg = w * 8 + rt * 4 + quad;
            int col = ct * 16 + lr;
            sh.ep.segA[seg][col] = A;
            sh.ep.segB[seg][col] = B;
        }
    __syncthreads();

    // ---- wave 0: chunk aggregate -> publish -> look-back -> seg states
    if (tid < BN) {
        float A = 1.f, B = 0.f;
        if (FWD) {
            #pragma unroll
            for (int sg = 0; sg < NSEG; ++sg) {
                float a = sh.ep.segA[sg][tid];
                A = a * A; B = fmaf(a, B, sh.ep.segB[sg][tid]);
            }
        } else {
            #pragma unroll
            for (int sg = NSEG - 1; sg >= 0; --sg) {
                float a = sh.ep.segA[sg][tid];
                A = a * A; B = fmaf(a, B, sh.ep.segB[sg][tid]);
            }
        }
        // publish local aggregate
        const int base = chain * NCH;
        const int idx  = (base + p) * BN + tid;
        locA[idx] = A; locB[idx] = B;
        __threadfence();
        if (tid == 0)
            __hip_atomic_store(&st[base + p], 1, __ATOMIC_RELEASE, __HIP_MEMORY_SCOPE_AGENT);

        // decoupled look-back for incoming state h0
        float h0 = 0.f;
        if (p > 0) {
            float Ar = 1.f, Br = 0.f;     // affine over (pp+1 .. p-1)
            int pp = p - 1;
            for (;;) {
                int s = __hip_atomic_load(&st[base + pp], __ATOMIC_ACQUIRE, __HIP_MEMORY_SCOPE_AGENT);
                if (s == 0) { __builtin_amdgcn_s_sleep(1); continue; }
                int j = (base + pp) * BN + tid;
                if (s == 2) {
                    float hp = __hip_atomic_load(&pre[j], __ATOMIC_RELAXED, __HIP_MEMORY_SCOPE_AGENT);
                    h0 = fmaf(Ar, hp, Br);
                    break;
                }
                float Ap = __hip_atomic_load(&locA[j], __ATOMIC_RELAXED, __HIP_MEMORY_SCOPE_AGENT);
                float Bp = __hip_atomic_load(&locB[j], __ATOMIC_RELAXED, __HIP_MEMORY_SCOPE_AGENT);
                Br = fmaf(Ar, Bp, Br);
                Ar = Ar * Ap;
                if (--pp < 0) { h0 = Br; break; }
            }
        }
        // publish inclusive prefix state
        float hincl = fmaf(A, h0, B);
        pre[(base + p) * BN + tid] = hincl;
        __threadfence();
        if (tid == 0)
            __hip_atomic_store(&st[base + p], 2, __ATOMIC_RELEASE, __HIP_MEMORY_SCOPE_AGENT);

        if (MODE == 2) {
            if (p == NCH - 1) outp[n0 + tid] = hincl;
        } else {
            // segment-start states for replay
            float h = h0;
            if (FWD) {
                #pragma unroll
                for (int sg = 0; sg < NSEG; ++sg) {
                    sh.ep.hseg[sg][tid] = h;
                    h = fmaf(sh.ep.segA[sg][tid], h, sh.ep.segB[sg][tid]);
                }
            } else {
                #pragma unroll
                for (int sg = NSEG - 1; sg >= 0; --sg) {
                    sh.ep.hseg[sg][tid] = h;
                    h = fmaf(sh.ep.segA[sg][tid], h, sh.ep.segB[sg][tid]);
                }
            }
        }
    }

    if (MODE != 2) {
        __syncthreads();
        #pragma unroll
        for (int rt = 0; rt < 2; ++rt)
            #pragma unroll
            for (int ct = 0; ct < 4; ++ct) {
                int seg = w * 8 + rt * 4 + quad;
                int col = ct * 16 + lr;
                float h = sh.ep.hseg[seg][col];
                if (FWD) {
                    #pragma unroll
                    for (int r = 0; r < 4; ++r) {
                        h = fmaf(av[rt][ct][r], h, bv[rt][ct][r]);
                        sh.ep.hout[w * 32 + rt * 16 + quad * 4 + r][col] = f2b(h);
                    }
                } else {
                    #pragma unroll
                    for (int r = 3; r >= 0; --r) {
                        h = fmaf(av[rt][ct][r], h, bv[rt][ct][r]);
                        sh.ep.hout[w * 32 + rt * 16 + quad * 4 + r][col] = f2b(h);
                    }
                }
            }
        __syncthreads();
        #pragma unroll
        for (int s = 0; s < 4; ++s) {
            int id = tid + 256 * s;
            int r = id >> 3, g = id & 7;
            short8 hv = *(const short8*)&sh.ep.hout[r][g * 8];
            u16* gp = hout + (size_t)(t0 + r) * D + n0 + g * 8;
            if (MODE == 0) {
                *(short8*)gp = hv;
            } else {
                short8 old = *(const short8*)gp;
                short8 nv;
                #pragma unroll
                for (int i = 0; i < 8; ++i)
                    nv[i] = (short)f2b(b2f((u16)old[i]) + b2f((u16)hv[i]));
                *(short8*)gp = nv;
            }
        }
    }
}

// ===========================================================================
// TIER B fallback (small workspace): R4 path — compute-staged GEMM,
// phase0/phase1 + separate inter-chunk scan.
// ===========================================================================
template<int FWD, int PHASE>
__global__ __launch_bounds__(256) void qrn_gemm_b(
    const float* __restrict__ xf, const u16* __restrict__ qg,
    const u16* __restrict__ wt,
    const float* __restrict__ bz, const float* __restrict__ bh,
    float* __restrict__ aggA, float* __restrict__ aggB,
    const float* __restrict__ hinit, u16* __restrict__ hout)
{
    __shared__ SharedU sh;
    const int tid  = threadIdx.x;
    const int gidx = ((int)blockIdx.x & 7) * 256 + ((int)blockIdx.x >> 3);
    const int c    = gidx >> 2;
    const int n0   = (gidx & 3) * BN;
    const int t0   = c * BT;
    const int lane = tid & 63, w = tid >> 6;
    const int lr   = lane & 15, quad = lane >> 4;

    int offA[2], offB[4];
    #pragma unroll
    for (int rt = 0; rt < 2; ++rt) {
        int row = w * 32 + rt * 16 + lr;
        offA[rt] = row * 32 + (quad ^ ((row >> 1) & 3)) * 8;
    }
    #pragma unroll
    for (int ct = 0; ct < 4; ++ct) {
        int n = ct * 16 + lr;
        offB[ct] = n * 32 + (quad ^ ((n >> 1) & 3)) * 8;
    }

    floatx4 accz[2][4], acch[2][4];
    #pragma unroll
    for (int rt = 0; rt < 2; ++rt)
        #pragma unroll
        for (int ct = 0; ct < 4; ++ct) {
            accz[rt][ct] = (floatx4){0.f,0.f,0.f,0.f};
            acch[rt][ct] = (floatx4){0.f,0.f,0.f,0.f};
        }

    const u16* wz = wt;
    const u16* wx = wt + 65536;
    const u16* wq = wt + 131072;
    const int wbase = (tid & ~63) * 8;

    for (int k0 = 0; k0 < D; k0 += 32) {
        #pragma unroll
        for (int i = 0; i < 2; ++i) {
            int id = i * 256 + tid;
            int row = id >> 2, sl = id & 3;
            int gg = sl ^ ((row >> 1) & 3);
            const float* xp = xf + (size_t)(t0 + row) * D + k0 + gg * 8;
            float4 xa = *(const float4*)xp;
            float4 xc = *(const float4*)(xp + 4);
            short8 q8 = *(const short8*)(qg + (size_t)(t0 + row) * D + k0 + gg * 8);
            float xv[8] = {xa.x, xa.y, xa.z, xa.w, xc.x, xc.y, xc.z, xc.w};
            short8 x8, xq8;
            #pragma unroll
            for (int e = 0; e < 8; ++e) {
                float qf = b2f((u16)q8[e]);
                x8[e]  = (short)f2b(xv[e]);
                xq8[e] = (short)f2b(xv[e] * qf);
            }
            int lb = id * 8;
            *(short8*)(sh.st.ax  + lb) = x8;
            *(short8*)(sh.st.aq  + lb) = q8;
            *(short8*)(sh.st.axq + lb) = xq8;
        }
        {
            int n = tid >> 2, sl = tid & 3;
            int gg = sl ^ ((n >> 1) & 3);
            size_t go = (size_t)(n0 + n) * D + k0 + gg * 8;
            async16(wz + go, sh.st.bz_ + wbase);
            async16(wx + go, sh.st.bx_ + wbase);
            async16(wq + go, sh.st.bq_ + wbase);
        }
        __syncthreads();

        short8 fx[2], fq[2], fxq[2];
        #pragma unroll
        for (int rt = 0; rt < 2; ++rt) {
            fx [rt] = *(const short8*)(sh.st.ax  + offA[rt]);
            fq [rt] = *(const short8*)(sh.st.aq  + offA[rt]);
            fxq[rt] = *(const short8*)(sh.st.axq + offA[rt]);
        }
        #pragma unroll
        for (int ct = 0; ct < 4; ++ct) {
            short8 vz = *(const short8*)(sh.st.bz_ + offB[ct]);
            short8 vx = *(const short8*)(sh.st.bx_ + offB[ct]);
            short8 vq = *(const short8*)(sh.st.bq_ + offB[ct]);
            #pragma unroll
            for (int rt = 0; rt < 2; ++rt) {
                accz[rt][ct] = __builtin_amdgcn_mfma_f32_16x16x32_bf16(fxq[rt], vz, accz[rt][ct], 0, 0, 0);
                acch[rt][ct] = __builtin_amdgcn_mfma_f32_16x16x32_bf16(fx [rt], vx, acch[rt][ct], 0, 0, 0);
                acch[rt][ct] = __builtin_amdgcn_mfma_f32_16x16x32_bf16(fq [rt], vq, acch[rt][ct], 0, 0, 0);
            }
        }
        __syncthreads();
    }

    float av[2][4][4], bv[2][4][4];
    #pragma unroll
    for (int ct = 0; ct < 4; ++ct) {
        int n = n0 + ct * 16 + lr;
        float bzn = bz[n], bhn = bh[n];
        #pragma unroll
        for (int rt = 0; rt < 2; ++rt)
            #pragma unroll
            for (int r = 0; r < 4; ++r) {
                float z  = sigm(accz[rt][ct][r] + bzn);
                float ht = tanhfast(acch[rt][ct][r] + bhn);
                av[rt][ct][r] = 1.0f - z;
                bv[rt][ct][r] = z * ht;
            }
    }
    #pragma unroll
    for (int rt = 0; rt < 2; ++rt)
        #pragma unroll
        for (int ct = 0; ct < 4; ++ct) {
            float A = 1.f, B = 0.f;
            if (FWD) {
                #pragma unroll
                for (int r = 0; r < 4; ++r) { A = av[rt][ct][r] * A; B = fmaf(av[rt][ct][r], B, bv[rt][ct][r]); }
            } else {
                #pragma unroll
                for (int r = 3; r >= 0; --r) { A = av[rt][ct][r] * A; B = fmaf(av[rt][ct][r], B, bv[rt][ct][r]); }
            }
            int seg = w * 8 + rt * 4 + quad;
            int col = ct * 16 + lr;
            sh.ep.segA[seg][col] = A;
            sh.ep.segB[seg][col] = B;
        }
    __syncthreads();

    if (PHASE == 0) {
        if (tid < BN) {
            float A = 1.f, B = 0.f;
            if (FWD) {
                #pragma unroll
                for (int sg = 0; sg < NSEG; ++sg) {
                    float a = sh.ep.segA[sg][tid];
                    A = a * A; B = fmaf(a, B, sh.ep.segB[sg][tid]);
                }
            } else {
                #pragma unroll
                for (int sg = NSEG - 1; sg >= 0; --sg) {
                    float a = sh.ep.segA[sg][tid];
                    A = a * A; B = fmaf(a, B, sh.ep.segB[sg][tid]);
                }
            }
            aggA[(size_t)c * D + n0 + tid] = A;
            aggB[(size_t)c * D + n0 + tid] = B;
        }
    } else {
        if (tid < BN) {
            float h = hinit[(size_t)c * D + n0 + tid];
            if (FWD) {
                #pragma unroll
                for (int sg = 0; sg < NSEG; ++sg) {
                    sh.ep.hseg[sg][tid] = h;
                    h = fmaf(sh.ep.segA[sg][tid], h, sh.ep.segB[sg][tid]);
                }
            } else {
                #pragma unroll
                for (int sg = NSEG - 1; sg >= 0; --sg) {
                    sh.ep.hseg[sg][tid] = h;
                    h = fmaf(sh.ep.segA[sg][tid], h, sh.ep.segB[sg][tid]);
                }
            }
        }
        __syncthreads();
        #pragma unroll
        for (int rt = 0; rt < 2; ++rt)
            #pragma unroll
            for (int ct = 0; ct < 4; ++ct) {
                int seg = w * 8 + rt * 4 + quad;
                int col = ct * 16 + lr;
                float h = sh.ep.hseg[seg][col];
                if (FWD) {
                    #pragma unroll
                    for (int r = 0; r < 4; ++r) {
                        h = fmaf(av[rt][ct][r], h, bv[rt][ct][r]);
                        sh.ep.hout[w * 32 + rt * 16 + quad * 4 + r][col] = f2b(h);
                    }
                } else {
                    #pragma unroll
                    for (int r = 3; r >= 0; --r) {
                        h = fmaf(av[rt][ct][r], h, bv[rt][ct][r]);
                        sh.ep.hout[w * 32 + rt * 16 + quad * 4 + r][col] = f2b(h);
                    }
                }
            }
        __syncthreads();
        #pragma unroll
        for (int s = 0; s < 4; ++s) {
            int id = tid + 256 * s;
            int r = id >> 3, g = id & 7;
            short8 hv = *(const short8*)&sh.ep.hout[r][g * 8];
            u16* gp = hout + (size_t)(t0 + r) * D + n0 + g * 8;
            if (FWD) {
                *(short8*)gp = hv;
            } else {
                short8 old = *(const short8*)gp;
                short8 nv;
                #pragma unroll
                for (int i = 0; i < 8; ++i)
                    nv[i] = (short)f2b(b2f((u16)old[i]) + b2f((u16)hv[i]));
                *(short8*)gp = nv;
            }
        }
    }
}

__global__ __launch_bounds__(256) void scan_p2_kernel(
    const float* __restrict__ aggA, const float* __restrict__ aggB,
    float* __restrict__ hinit, float* __restrict__ out_final, int fwd, int nch)
{
    __shared__ float sA[256], sB[256];
    const int n = blockIdx.x, tid = threadIdx.x;
    const int per = nch >> 8;
    float lA[4], lB[4];
    float A = 1.f, B = 0.f;
    for (int j = 0; j < per; ++j) {
        int pidx = tid * per + j;
        int c = fwd ? pidx : (nch - 1 - pidx);
        float a = aggA[(size_t)c * D + n];
        float b = aggB[(size_t)c * D + n];
        lA[j] = a; lB[j] = b;
        A = a * A;
        B = fmaf(a, B, b);
    }
    sA[tid] = A; sB[tid] = B;
    __syncthreads();
    for (int off = 1; off < 256; off <<= 1) {
        float pA = 1.f, pB = 0.f;
        if (tid >= off) { pA = sA[tid - off]; pB = sB[tid - off]; }
        __syncthreads();
        if (tid >= off) {
            float cA = sA[tid], cB = sB[tid];
            sA[tid] = pA * cA;
            sB[tid] = fmaf(cA, pB, cB);
        }
        __syncthreads();
    }
    float eB = (tid > 0) ? sB[tid - 1] : 0.f;
    for (int j = 0; j < per; ++j) {
        int pidx = tid * per + j;
        int c = fwd ? pidx : (nch - 1 - pidx);
        hinit[(size_t)c * D + n] = eB;
        eB = fmaf(lA[j], eB, lB[j]);
    }
    if (out_final != nullptr && tid == 0) out_final[n] = sB[255];
}

// ---------------------------------------------------------------------------
extern "C" void kernel_launch(void* const* d_in, const int* in_sizes, int n_in,
                              void* d_out, int out_size, void* d_ws, size_t ws_size,
                              hipStream_t stream) {
    const float* story    = (const float*)d_in[0];
    const float* question = (const float*)d_in[1];
    const float* Wz_f = (const float*)d_in[2];
    const float* bz_f = (const float*)d_in[3];
    const float* Wh_f = (const float*)d_in[4];
    const float* bh_f = (const float*)d_in[5];
    const float* Wz_b = (const float*)d_in[6];
    const float* bz_b = (const float*)d_in[7];
    const float* Wh_b = (const float*)d_in[8];
    const float* bh_b = (const float*)d_in[9];

    const int T    = in_sizes[0] / D;            // 65536
    const int NCH  = T / BT;                     // 512
    const size_t TD = (size_t)T * D;
    const size_t WTE = 5 * 3 * 65536;
    const size_t CHE = (size_t)4 * NCH * BN;     // elems per loc/pre array

    // Tier A: xb,qA,qB,xq + wt + ctrl + locA/locB/pre
    const size_t ctrlN  = 4 * (size_t)NCH + 64;  // st[4*NCH] + tickets + pad (ints)
    const size_t needA  = 4 * TD * 2 + WTE * 2 + ctrlN * 4 + 3 * CHE * 4;
    const bool bigws = ws_size >= needA;

    dim3 blk(256);
    dim3 gGrid((unsigned)(NCH * 4));             // 2048 blocks
    dim3 pGrid((unsigned)(TD / 8 / 256));

    if (bigws) {
        u16* xb = (u16*)d_ws;
        u16* qA = xb + TD;
        u16* qB = qA + TD;
        u16* xq = qB + TD;
        u16* wt = xq + TD;
        int* ctrl   = (int*)(wt + WTE);
        int* stf    = ctrl;                      // st[4*NCH]
        int* tick   = ctrl + 4 * NCH;            // tickets[4]
        float* locA = (float*)(ctrl + ctrlN);
        float* locB = locA + CHE;
        float* pre  = locB + CHE;
        float* outp = (float*)d_out;

        wtrans_kernel<<<dim3(5 * 3 * 65536 / 256), blk, 0, stream>>>(
            Wz_f, Wh_f, Wz_b, Wh_b, wt);
        prep0_kernel<<<pGrid, blk, 0, stream>>>(story, question, xb, qA, xq);

        const u16* qcur  = qA;
        u16*       qnext = qB;
        const size_t ctrlBytes = ctrlN * 4;

        for (int l = 0; l < 3; ++l) {
            const u16*   wtf = wt + (size_t)l * 3 * 65536;
            const float* bzf = bz_f + (size_t)l * D;
            const float* bhf = bh_f + (size_t)l * D;

            if (l == 2) {
                hipMemsetAsync(ctrl, 0, ctrlBytes, stream);
                qrn_fused<1,2><<<gGrid, blk, 0, stream>>>(
                    xb, qcur, xq, wtf, bzf, bhf,
                    stf, tick, locA, locB, pre, nullptr, outp);
                break;
            }
            const u16*   wtb = wt + (size_t)(3 + l) * 3 * 65536;
            const float* bzb = bz_b + (size_t)l * D;
            const float* bhb = bh_b + (size_t)l * D;

            hipMemsetAsync(ctrl, 0, ctrlBytes, stream);
            qrn_fused<1,0><<<gGrid, blk, 0, stream>>>(
                xb, qcur, xq, wtf, bzf, bhf,
                stf, tick, locA, locB, pre, qnext, nullptr);
            hipMemsetAsync(ctrl, 0, ctrlBytes, stream);
            qrn_fused<0,1><<<gGrid, blk, 0, stream>>>(
                xb, qcur, xq, wtb, bzb, bhb,
                stf, tick, locA, locB, pre, qnext, nullptr);
            xq_upd_kernel<<<pGrid, blk, 0, stream>>>(xb, qnext, xq);

            const u16* ts = qcur; qcur = qnext; qnext = (u16*)ts;
        }
    } else {
        // ---------------- Tier B fallback (R4 path) ----------------
        u16* qA = (u16*)d_ws;
        u16* qB = qA + TD;
        u16* wt = qB + TD;
        float* aggA = (float*)(wt + WTE);
        float* aggB = aggA + (size_t)NCH * D;
        float* hini = aggB;

        wtrans_kernel<<<dim3(5 * 3 * 65536 / 256), blk, 0, stream>>>(
            Wz_f, Wh_f, Wz_b, Wh_b, wt);
        q_init_kernel<<<pGrid, blk, 0, stream>>>(qA, question, (long)(TD / 8));

        const u16* qcur  = qA;
        u16*       qnext = qB;

        for (int l = 0; l < 3; ++l) {
            const u16*   wtf = wt + (size_t)l * 3 * 65536;
            const float* bzf = bz_f + (size_t)l * D;
            const float* bhf = bh_f + (size_t)l * D;

            if (l == 2) {
                qrn_gemm_b<1,0><<<gGrid, blk, 0, stream>>>(story, qcur,
                    wtf, bzf, bhf, aggA, aggB, nullptr, nullptr);
                scan_p2_kernel<<<dim3(D), blk, 0, stream>>>(
                    aggA, aggB, hini, (float*)d_out, 1, NCH);
                break;
            }
            const u16*   wtb = wt + (size_t)(3 + l) * 3 * 65536;
            const float* bzb = bz_b + (size_t)l * D;
            const float* bhb = bh_b + (size_t)l * D;

            qrn_gemm_b<1,0><<<gGrid, blk, 0, stream>>>(story, qcur,
                wtf, bzf, bhf, aggA, aggB, nullptr, nullptr);
            scan_p2_kernel<<<dim3(D), blk, 0, stream>>>(aggA, aggB, hini, nullptr, 1, NCH);
            qrn_gemm_b<1,1><<<gGrid, blk, 0, stream>>>(story, qcur,
                wtf, bzf, bhf, nullptr, nullptr, hini, qnext);

            qrn_gemm_b<0,0><<<gGrid, blk, 0, stream>>>(story, qcur,
                wtb, bzb, bhb, aggA, aggB, nullptr, nullptr);
            scan_p2_kernel<<<dim3(D), blk, 0, stream>>>(aggA, aggB, hini, nullptr, 0, NCH);
            qrn_gemm_b<0,1><<<gGrid, blk, 0, stream>>>(story, qcur,
                wtb, bzb, bhb, nullptr, nullptr, hini, qnext);

            const u16* ts = qcur; qcur = qnext; qnext = (u16*)ts;
        }
    }
}

// Round 6
// 683.316 us; speedup vs baseline: 4.0116x; 4.0116x over previous
//
#include <hip/hip_runtime.h>
#include <hip/hip_bf16.h>
#include <math.h>

#define D    256
#define BT   128     // chunk length == M tile
#define BN   64      // N tile per block (4 N-slices)
#define NSEG 32      // BT/4 segments per chunk (GEMM epilogue)

typedef unsigned short u16;
typedef unsigned int   u32;
typedef __attribute__((ext_vector_type(8))) short short8;   // 8 bf16 = 4 VGPRs
typedef __attribute__((ext_vector_type(4))) float floatx4;  // MFMA C/D frag

__device__ __forceinline__ float b2f(u16 v) {
    union { unsigned u; float f; } x; x.u = ((unsigned)v) << 16; return x.f;
}
__device__ __forceinline__ u16 f2b(float f) {
    union { unsigned u; float f; } x; x.f = f;
    unsigned lsb = (x.u >> 16) & 1;
    x.u += 0x7fffu + lsb;                 // RNE
    return (u16)(x.u >> 16);
}
__device__ __forceinline__ float sigm(float x) {
    return __builtin_amdgcn_rcpf(1.0f + __expf(-x));
}
__device__ __forceinline__ float tanhfast(float x) {
    return 1.0f - 2.0f * __builtin_amdgcn_rcpf(__expf(2.0f * x) + 1.0f);
}
__device__ __forceinline__ void async16(const u16* g, u16* l) {
    __builtin_amdgcn_global_load_lds(
        (const __attribute__((address_space(1))) unsigned int*)g,
        (__attribute__((address_space(3))) unsigned int*)l, 16, 0, 0);
}

// ---------------------------------------------------------------------------
// weight transpose + bf16 cast: wt[combo][m][n][k] = bf16(W[k][n])
// ---------------------------------------------------------------------------
__global__ __launch_bounds__(256) void wtrans_kernel(
    const float* __restrict__ Wz_f, const float* __restrict__ Wh_f,
    const float* __restrict__ Wz_b, const float* __restrict__ Wh_b,
    u16* __restrict__ wt)
{
    int id = blockIdx.x * 256 + threadIdx.x;       // < 5*3*65536
    int combo = id / (3 * 65536);
    int rem   = id % (3 * 65536);
    int m = rem >> 16;
    int e = rem & 65535;
    int k = e >> 8, n = e & 255;
    int l   = combo < 3 ? combo : combo - 3;
    int dir = combo < 3 ? 0 : 1;
    float v;
    if (m == 0) {
        const float* Wz = dir ? Wz_b : Wz_f;
        v = Wz[((size_t)l * D + k) * D + n];
    } else {
        const float* Wh = dir ? Wh_b : Wh_f;
        int kk = (m == 2) ? (k + D) : k;
        v = Wh[((size_t)l * 2 * D + kk) * D + n];
    }
    wt[(size_t)combo * 3 * 65536 + (size_t)m * 65536 + (size_t)n * D + k] = f2b(v);
}

// ---------------------------------------------------------------------------
// prep: xb = bf16(x), q broadcast, xq = bf16(x*qbf)
// ---------------------------------------------------------------------------
__global__ __launch_bounds__(256) void prep0_kernel(
    const float* __restrict__ story, const float* __restrict__ question,
    u16* __restrict__ xb, u16* __restrict__ q, u16* __restrict__ xq)
{
    long id = (long)blockIdx.x * 256 + threadIdx.x;
    long row = id >> 5;
    int  d0  = (int)(id & 31) * 8;
    const float* xp = story + row * D + d0;
    float4 xa = *(const float4*)xp;
    float4 xc = *(const float4*)(xp + 4);
    float xv[8] = {xa.x, xa.y, xa.z, xa.w, xc.x, xc.y, xc.z, xc.w};
    short8 xs, qs, xqs;
    #pragma unroll
    for (int i = 0; i < 8; ++i) {
        u16 qb = f2b(question[d0 + i]);
        xs[i]  = (short)f2b(xv[i]);
        qs[i]  = (short)qb;
        xqs[i] = (short)f2b(xv[i] * b2f(qb));
    }
    long o = id * 8;
    *(short8*)(xb + o) = xs;
    *(short8*)(q  + o) = qs;
    *(short8*)(xq + o) = xqs;
}

// xq = bf16(b2f(xb) * b2f(qnew))  (fallback path only)
__global__ __launch_bounds__(256) void xq_upd_kernel(
    const u16* __restrict__ xb, const u16* __restrict__ qn, u16* __restrict__ xq)
{
    long id = (long)blockIdx.x * 256 + threadIdx.x;
    long o  = id * 8;
    short8 xs = *(const short8*)(xb + o);
    short8 qs = *(const short8*)(qn + o);
    short8 r;
    #pragma unroll
    for (int i = 0; i < 8; ++i)
        r[i] = (short)f2b(b2f((u16)xs[i]) * b2f((u16)qs[i]));
    *(short8*)(xq + o) = r;
}

// ---------------------------------------------------------------------------
// LDS stage layout (shared by GEMM kernels)
// ---------------------------------------------------------------------------
struct StageS {
    u16 ax [BT * 32]; u16 aq [BT * 32]; u16 axq[BT * 32];   // 8KB each
    u16 bz_[BN * 32]; u16 bx_[BN * 32]; u16 bq_[BN * 32];   // 4KB each
};

// ===========================================================================
// PLAN-P GEMM: gates GEMM -> chunk aggregate (+ optional packed a,b writeout)
// ABOUT=1: write ab[t*D+n] = u32{ bf16(a) | bf16(b)<<16 }
// ===========================================================================
struct EpiP { float segA[NSEG][BN]; float segB[NSEG][BN]; };
union SharedP { StageS st; EpiP ep; };

template<int FWD, int ABOUT>
__global__ __launch_bounds__(256) void qrn_g5(
    const u16* __restrict__ xbg, const u16* __restrict__ qg,
    const u16* __restrict__ xqg, const u16* __restrict__ wt,
    const float* __restrict__ bz, const float* __restrict__ bh,
    float* __restrict__ aggA, float* __restrict__ aggB,
    u32* __restrict__ abg)
{
    __shared__ SharedP sh;
    const int tid  = threadIdx.x;
    const int gidx = ((int)blockIdx.x & 7) * 256 + ((int)blockIdx.x >> 3);
    const int c    = gidx >> 2;
    const int n0   = (gidx & 3) * BN;
    const int t0   = c * BT;
    const int lane = tid & 63, w = tid >> 6;
    const int lr   = lane & 15, quad = lane >> 4;

    int offA[2], offB[4];
    #pragma unroll
    for (int rt = 0; rt < 2; ++rt) {
        int row = w * 32 + rt * 16 + lr;
        offA[rt] = row * 32 + (quad ^ ((row >> 1) & 3)) * 8;
    }
    #pragma unroll
    for (int ct = 0; ct < 4; ++ct) {
        int n = ct * 16 + lr;
        offB[ct] = n * 32 + (quad ^ ((n >> 1) & 3)) * 8;
    }

    floatx4 accz[2][4], acch[2][4];
    #pragma unroll
    for (int rt = 0; rt < 2; ++rt)
        #pragma unroll
        for (int ct = 0; ct < 4; ++ct) {
            accz[rt][ct] = (floatx4){0.f,0.f,0.f,0.f};
            acch[rt][ct] = (floatx4){0.f,0.f,0.f,0.f};
        }

    const u16* wz = wt;
    const u16* wx = wt + 65536;
    const u16* wq = wt + 131072;
    const int wbase = (tid & ~63) * 8;

    for (int k0 = 0; k0 < D; k0 += 32) {
        #pragma unroll
        for (int i = 0; i < 2; ++i) {
            int u = i * 256 + tid;
            int row = u >> 2, sl = u & 3;
            int gg = sl ^ ((row >> 1) & 3);
            size_t go = (size_t)(t0 + row) * D + k0 + gg * 8;
            int lb = (i * 256 + (tid & ~63)) * 8;
            async16(xbg + go, sh.st.ax  + lb);
            async16(qg  + go, sh.st.aq  + lb);
            async16(xqg + go, sh.st.axq + lb);
        }
        {
            int n = tid >> 2, sl = tid & 3;
            int gg = sl ^ ((n >> 1) & 3);
            size_t go = (size_t)(n0 + n) * D + k0 + gg * 8;
            async16(wz + go, sh.st.bz_ + wbase);
            async16(wx + go, sh.st.bx_ + wbase);
            async16(wq + go, sh.st.bq_ + wbase);
        }
        __syncthreads();

        short8 fx[2], fq[2], fxq[2];
        #pragma unroll
        for (int rt = 0; rt < 2; ++rt) {
            fx [rt] = *(const short8*)(sh.st.ax  + offA[rt]);
            fq [rt] = *(const short8*)(sh.st.aq  + offA[rt]);
            fxq[rt] = *(const short8*)(sh.st.axq + offA[rt]);
        }
        #pragma unroll
        for (int ct = 0; ct < 4; ++ct) {
            short8 vz = *(const short8*)(sh.st.bz_ + offB[ct]);
            short8 vx = *(const short8*)(sh.st.bx_ + offB[ct]);
            short8 vq = *(const short8*)(sh.st.bq_ + offB[ct]);
            #pragma unroll
            for (int rt = 0; rt < 2; ++rt) {
                accz[rt][ct] = __builtin_amdgcn_mfma_f32_16x16x32_bf16(fxq[rt], vz, accz[rt][ct], 0, 0, 0);
                acch[rt][ct] = __builtin_amdgcn_mfma_f32_16x16x32_bf16(fx [rt], vx, acch[rt][ct], 0, 0, 0);
                acch[rt][ct] = __builtin_amdgcn_mfma_f32_16x16x32_bf16(fq [rt], vq, acch[rt][ct], 0, 0, 0);
            }
        }
        __syncthreads();
    }

    // gate epilogue (C/D: col = lr, rows = quad*4 + r)
    float av[2][4][4], bv[2][4][4];
    #pragma unroll
    for (int ct = 0; ct < 4; ++ct) {
        int n = n0 + ct * 16 + lr;
        float bzn = bz[n], bhn = bh[n];
        #pragma unroll
        for (int rt = 0; rt < 2; ++rt)
            #pragma unroll
            for (int r = 0; r < 4; ++r) {
                float z  = sigm(accz[rt][ct][r] + bzn);
                float ht = tanhfast(acch[rt][ct][r] + bhn);
                av[rt][ct][r] = 1.0f - z;
                bv[rt][ct][r] = z * ht;
            }
    }

    // per-lane 4-step segment aggregates -> LDS
    #pragma unroll
    for (int rt = 0; rt < 2; ++rt)
        #pragma unroll
        for (int ct = 0; ct < 4; ++ct) {
            float A = 1.f, B = 0.f;
            if (FWD) {
                #pragma unroll
                for (int r = 0; r < 4; ++r) { A = av[rt][ct][r] * A; B = fmaf(av[rt][ct][r], B, bv[rt][ct][r]); }
            } else {
                #pragma unroll
                for (int r = 3; r >= 0; --r) { A = av[rt][ct][r] * A; B = fmaf(av[rt][ct][r], B, bv[rt][ct][r]); }
            }
            int seg = w * 8 + rt * 4 + quad;
            int col = ct * 16 + lr;
            sh.ep.segA[seg][col] = A;
            sh.ep.segB[seg][col] = B;
        }

    // packed a,b writeout (each quad's 16 lanes cover one 64B line)
    if (ABOUT) {
        #pragma unroll
        for (int rt = 0; rt < 2; ++rt)
            #pragma unroll
            for (int ct = 0; ct < 4; ++ct) {
                size_t base = (size_t)(t0 + w * 32 + rt * 16 + quad * 4) * D
                              + n0 + ct * 16 + lr;
                #pragma unroll
                for (int r = 0; r < 4; ++r) {
                    u32 pv = (u32)f2b(av[rt][ct][r]) | ((u32)f2b(bv[rt][ct][r]) << 16);
                    abg[base + (size_t)r * D] = pv;
                }
            }
    }
    __syncthreads();

    if (tid < BN) {
        float A = 1.f, B = 0.f;
        if (FWD) {
            #pragma unroll
            for (int sg = 0; sg < NSEG; ++sg) {
                float a = sh.ep.segA[sg][tid];
                A = a * A; B = fmaf(a, B, sh.ep.segB[sg][tid]);
            }
        } else {
            #pragma unroll
            for (int sg = NSEG - 1; sg >= 0; --sg) {
                float a = sh.ep.segA[sg][tid];
                A = a * A; B = fmaf(a, B, sh.ep.segB[sg][tid]);
            }
        }
        aggA[(size_t)c * D + n0 + tid] = A;
        aggB[(size_t)c * D + n0 + tid] = B;
    }
}

// ===========================================================================
// replay kernels: read packed a,b; seg-scan per channel; write h.
// Block = (chunk, 64-ch slice); 256 threads = 4 segs x 64 channels.
// ===========================================================================
__global__ __launch_bounds__(256) void replay_f(
    const u32* __restrict__ abg, const float* __restrict__ hini,
    u16* __restrict__ qout)
{
    __shared__ u32   sab[BT * BN];       // 32 KB
    __shared__ float sA[4][BN], sB[4][BN], hs[4][BN];
    const int tid = threadIdx.x;
    const int c   = (int)(blockIdx.x >> 2);
    const int n0  = ((int)blockIdx.x & 3) * BN;
    const int t0  = c * BT;

    #pragma unroll
    for (int i = 0; i < 8; ++i) {
        int idx = i * 256 + tid;            // 0..2047
        int row = idx >> 4, g = idx & 15;
        *(uint4*)(sab + row * BN + g * 4) =
            *(const uint4*)(abg + (size_t)(t0 + row) * D + n0 + g * 4);
    }
    __syncthreads();

    const int sg = tid >> 6, n = tid & 63;
    float A = 1.f, B = 0.f;
    #pragma unroll
    for (int i = 0; i < 32; ++i) {
        u32 v = sab[(sg * 32 + i) * BN + n];
        float a = b2f((u16)(v & 0xffff)), b = b2f((u16)(v >> 16));
        A = a * A; B = fmaf(a, B, b);
    }
    sA[sg][n] = A; sB[sg][n] = B;
    __syncthreads();
    if (tid < BN) {
        float h = hini[(size_t)c * D + n0 + tid];
        #pragma unroll
        for (int s = 0; s < 4; ++s) {
            hs[s][tid] = h;
            h = fmaf(sA[s][tid], h, sB[s][tid]);
        }
    }
    __syncthreads();
    float h = hs[sg][n];
    #pragma unroll
    for (int i = 0; i < 32; ++i) {
        int t = sg * 32 + i;
        u32 v = sab[t * BN + n];
        float a = b2f((u16)(v & 0xffff)), b = b2f((u16)(v >> 16));
        h = fmaf(a, h, b);
        qout[(size_t)(t0 + t) * D + n0 + n] = f2b(h);
    }
}

__global__ __launch_bounds__(256) void replay_b(
    const u32* __restrict__ abg, const float* __restrict__ hini,
    const u16* __restrict__ xb, u16* __restrict__ qout, u16* __restrict__ xq)
{
    __shared__ u32   sab[BT * BN];
    __shared__ float sA[4][BN], sB[4][BN], hs[4][BN];
    const int tid = threadIdx.x;
    const int c   = (int)(blockIdx.x >> 2);
    const int n0  = ((int)blockIdx.x & 3) * BN;
    const int t0  = c * BT;

    #pragma unroll
    for (int i = 0; i < 8; ++i) {
        int idx = i * 256 + tid;
        int row = idx >> 4, g = idx & 15;
        *(uint4*)(sab + row * BN + g * 4) =
            *(const uint4*)(abg + (size_t)(t0 + row) * D + n0 + g * 4);
    }
    __syncthreads();

    const int sg = tid >> 6, n = tid & 63;
    float A = 1.f, B = 0.f;
    #pragma unroll
    for (int i = 31; i >= 0; --i) {
        u32 v = sab[(sg * 32 + i) * BN + n];
        float a = b2f((u16)(v & 0xffff)), b = b2f((u16)(v >> 16));
        A = a * A; B = fmaf(a, B, b);
    }
    sA[sg][n] = A; sB[sg][n] = B;
    __syncthreads();
    if (tid < BN) {
        float h = hini[(size_t)c * D + n0 + tid];
        for (int s = 3; s >= 0; --s) {
            hs[s][tid] = h;
            h = fmaf(sA[s][tid], h, sB[s][tid]);
        }
    }
    __syncthreads();
    float h = hs[sg][n];
    #pragma unroll
    for (int i = 31; i >= 0; --i) {
        int t = sg * 32 + i;
        u32 v = sab[t * BN + n];
        float a = b2f((u16)(v & 0xffff)), b = b2f((u16)(v >> 16));
        h = fmaf(a, h, b);
        size_t o = (size_t)(t0 + t) * D + n0 + n;
        float qn = b2f(qout[o]) + h;       // hF + hB
        u16 qb = f2b(qn);
        qout[o] = qb;
        xq[o]   = f2b(b2f(xb[o]) * b2f(qb));
    }
}

// ===========================================================================
// FALLBACK (R4 tier-A): GEMM with PHASE 0/1 (recompute) + hseg/hout epilogue
// ===========================================================================
struct EpiS {
    float segA[NSEG][BN]; float segB[NSEG][BN]; float hseg[NSEG][BN];
    u16   hout[BT][BN];
};
union SharedU { StageS st; EpiS ep; };

template<int FWD, int PHASE>
__global__ __launch_bounds__(256) void qrn_gemm_fb(
    const u16* __restrict__ xbg, const u16* __restrict__ qg,
    const u16* __restrict__ xqg, const u16* __restrict__ wt,
    const float* __restrict__ bz, const float* __restrict__ bh,
    float* __restrict__ aggA, float* __restrict__ aggB,
    const float* __restrict__ hinit, u16* __restrict__ hout)
{
    __shared__ SharedU sh;
    const int tid  = threadIdx.x;
    const int gidx = ((int)blockIdx.x & 7) * 256 + ((int)blockIdx.x >> 3);
    const int c    = gidx >> 2;
    const int n0   = (gidx & 3) * BN;
    const int t0   = c * BT;
    const int lane = tid & 63, w = tid >> 6;
    const int lr   = lane & 15, quad = lane >> 4;

    int offA[2], offB[4];
    #pragma unroll
    for (int rt = 0; rt < 2; ++rt) {
        int row = w * 32 + rt * 16 + lr;
        offA[rt] = row * 32 + (quad ^ ((row >> 1) & 3)) * 8;
    }
    #pragma unroll
    for (int ct = 0; ct < 4; ++ct) {
        int n = ct * 16 + lr;
        offB[ct] = n * 32 + (quad ^ ((n >> 1) & 3)) * 8;
    }

    floatx4 accz[2][4], acch[2][4];
    #pragma unroll
    for (int rt = 0; rt < 2; ++rt)
        #pragma unroll
        for (int ct = 0; ct < 4; ++ct) {
            accz[rt][ct] = (floatx4){0.f,0.f,0.f,0.f};
            acch[rt][ct] = (floatx4){0.f,0.f,0.f,0.f};
        }

    const u16* wz = wt;
    const u16* wx = wt + 65536;
    const u16* wq = wt + 131072;
    const int wbase = (tid & ~63) * 8;

    for (int k0 = 0; k0 < D; k0 += 32) {
        #pragma unroll
        for (int i = 0; i < 2; ++i) {
            int u = i * 256 + tid;
            int row = u >> 2, sl = u & 3;
            int gg = sl ^ ((row >> 1) & 3);
            size_t go = (size_t)(t0 + row) * D + k0 + gg * 8;
            int lb = (i * 256 + (tid & ~63)) * 8;
            async16(xbg + go, sh.st.ax  + lb);
            async16(qg  + go, sh.st.aq  + lb);
            async16(xqg + go, sh.st.axq + lb);
        }
        {
            int n = tid >> 2, sl = tid & 3;
            int gg = sl ^ ((n >> 1) & 3);
            size_t go = (size_t)(n0 + n) * D + k0 + gg * 8;
            async16(wz + go, sh.st.bz_ + wbase);
            async16(wx + go, sh.st.bx_ + wbase);
            async16(wq + go, sh.st.bq_ + wbase);
        }
        __syncthreads();

        short8 fx[2], fq[2], fxq[2];
        #pragma unroll
        for (int rt = 0; rt < 2; ++rt) {
            fx [rt] = *(const short8*)(sh.st.ax  + offA[rt]);
            fq [rt] = *(const short8*)(sh.st.aq  + offA[rt]);
            fxq[rt] = *(const short8*)(sh.st.axq + offA[rt]);
        }
        #pragma unroll
        for (int ct = 0; ct < 4; ++ct) {
            short8 vz = *(const short8*)(sh.st.bz_ + offB[ct]);
            short8 vx = *(const short8*)(sh.st.bx_ + offB[ct]);
            short8 vq = *(const short8*)(sh.st.bq_ + offB[ct]);
            #pragma unroll
            for (int rt = 0; rt < 2; ++rt) {
                accz[rt][ct] = __builtin_amdgcn_mfma_f32_16x16x32_bf16(fxq[rt], vz, accz[rt][ct], 0, 0, 0);
                acch[rt][ct] = __builtin_amdgcn_mfma_f32_16x16x32_bf16(fx [rt], vx, acch[rt][ct], 0, 0, 0);
                acch[rt][ct] = __builtin_amdgcn_mfma_f32_16x16x32_bf16(fq [rt], vq, acch[rt][ct], 0, 0, 0);
            }
        }
        __syncthreads();
    }

    float av[2][4][4], bv[2][4][4];
    #pragma unroll
    for (int ct = 0; ct < 4; ++ct) {
        int n = n0 + ct * 16 + lr;
        float bzn = bz[n], bhn = bh[n];
        #pragma unroll
        for (int rt = 0; rt < 2; ++rt)
            #pragma unroll
            for (int r = 0; r < 4; ++r) {
                float z  = sigm(accz[rt][ct][r] + bzn);
                float ht = tanhfast(acch[rt][ct][r] + bhn);
                av[rt][ct][r] = 1.0f - z;
                bv[rt][ct][r] = z * ht;
            }
    }
    #pragma unroll
    for (int rt = 0; rt < 2; ++rt)
        #pragma unroll
        for (int ct = 0; ct < 4; ++ct) {
            float A = 1.f, B = 0.f;
            if (FWD) {
                #pragma unroll
                for (int r = 0; r < 4; ++r) { A = av[rt][ct][r] * A; B = fmaf(av[rt][ct][r], B, bv[rt][ct][r]); }
            } else {
                #pragma unroll
                for (int r = 3; r >= 0; --r) { A = av[rt][ct][r] * A; B = fmaf(av[rt][ct][r], B, bv[rt][ct][r]); }
            }
            int seg = w * 8 + rt * 4 + quad;
            int col = ct * 16 + lr;
            sh.ep.segA[seg][col] = A;
            sh.ep.segB[seg][col] = B;
        }
    __syncthreads();

    if (PHASE == 0) {
        if (tid < BN) {
            float A = 1.f, B = 0.f;
            if (FWD) {
                #pragma unroll
                for (int sg = 0; sg < NSEG; ++sg) {
                    float a = sh.ep.segA[sg][tid];
                    A = a * A; B = fmaf(a, B, sh.ep.segB[sg][tid]);
                }
            } else {
                #pragma unroll
                for (int sg = NSEG - 1; sg >= 0; --sg) {
                    float a = sh.ep.segA[sg][tid];
                    A = a * A; B = fmaf(a, B, sh.ep.segB[sg][tid]);
                }
            }
            aggA[(size_t)c * D + n0 + tid] = A;
            aggB[(size_t)c * D + n0 + tid] = B;
        }
    } else {
        if (tid < BN) {
            float h = hinit[(size_t)c * D + n0 + tid];
            if (FWD) {
                #pragma unroll
                for (int sg = 0; sg < NSEG; ++sg) {
                    sh.ep.hseg[sg][tid] = h;
                    h = fmaf(sh.ep.segA[sg][tid], h, sh.ep.segB[sg][tid]);
                }
            } else {
                #pragma unroll
                for (int sg = NSEG - 1; sg >= 0; --sg) {
                    sh.ep.hseg[sg][tid] = h;
                    h = fmaf(sh.ep.segA[sg][tid], h, sh.ep.segB[sg][tid]);
                }
            }
        }
        __syncthreads();
        #pragma unroll
        for (int rt = 0; rt < 2; ++rt)
            #pragma unroll
            for (int ct = 0; ct < 4; ++ct) {
                int seg = w * 8 + rt * 4 + quad;
                int col = ct * 16 + lr;
                float h = sh.ep.hseg[seg][col];
                if (FWD) {
                    #pragma unroll
                    for (int r = 0; r < 4; ++r) {
                        h = fmaf(av[rt][ct][r], h, bv[rt][ct][r]);
                        sh.ep.hout[w * 32 + rt * 16 + quad * 4 + r][col] = f2b(h);
                    }
                } else {
                    #pragma unroll
                    for (int r = 3; r >= 0; --r) {
                        h = fmaf(av[rt][ct][r], h, bv[rt][ct][r]);
                        sh.ep.hout[w * 32 + rt * 16 + quad * 4 + r][col] = f2b(h);
                    }
                }
            }
        __syncthreads();
        #pragma unroll
        for (int s = 0; s < 4; ++s) {
            int id = tid + 256 * s;
            int r = id >> 3, g = id & 7;
            short8 hv = *(const short8*)&sh.ep.hout[r][g * 8];
            u16* gp = hout + (size_t)(t0 + r) * D + n0 + g * 8;
            if (FWD) {
                *(short8*)gp = hv;
            } else {
                short8 old = *(const short8*)gp;
                short8 nv;
                #pragma unroll
                for (int i = 0; i < 8; ++i)
                    nv[i] = (short)f2b(b2f((u16)old[i]) + b2f((u16)hv[i]));
                *(short8*)gp = nv;
            }
        }
    }
}

// ---------------------------------------------------------------------------
// inter-chunk scan (proven): one block per channel, Hillis-Steele over NCH.
// ---------------------------------------------------------------------------
__global__ __launch_bounds__(256) void scan_p2_kernel(
    const float* __restrict__ aggA, const float* __restrict__ aggB,
    float* __restrict__ hinit, float* __restrict__ out_final, int fwd, int nch)
{
    __shared__ float sA[256], sB[256];
    const int n = blockIdx.x, tid = threadIdx.x;
    const int per = nch >> 8;
    float lA[4], lB[4];
    float A = 1.f, B = 0.f;
    for (int j = 0; j < per; ++j) {
        int pidx = tid * per + j;
        int c = fwd ? pidx : (nch - 1 - pidx);
        float a = aggA[(size_t)c * D + n];
        float b = aggB[(size_t)c * D + n];
        lA[j] = a; lB[j] = b;
        A = a * A;
        B = fmaf(a, B, b);
    }
    sA[tid] = A; sB[tid] = B;
    __syncthreads();
    for (int off = 1; off < 256; off <<= 1) {
        float pA = 1.f, pB = 0.f;
        if (tid >= off) { pA = sA[tid - off]; pB = sB[tid - off]; }
        __syncthreads();
        if (tid >= off) {
            float cA = sA[tid], cB = sB[tid];
            sA[tid] = pA * cA;
            sB[tid] = fmaf(cA, pB, cB);
        }
        __syncthreads();
    }
    float eB = (tid > 0) ? sB[tid - 1] : 0.f;
    for (int j = 0; j < per; ++j) {
        int pidx = tid * per + j;
        int c = fwd ? pidx : (nch - 1 - pidx);
        hinit[(size_t)c * D + n] = eB;
        eB = fmaf(lA[j], eB, lB[j]);
    }
    if (out_final != nullptr && tid == 0) out_final[n] = sB[255];
}

// ---------------------------------------------------------------------------
extern "C" void kernel_launch(void* const* d_in, const int* in_sizes, int n_in,
                              void* d_out, int out_size, void* d_ws, size_t ws_size,
                              hipStream_t stream) {
    const float* story    = (const float*)d_in[0];
    const float* question = (const float*)d_in[1];
    const float* Wz_f = (const float*)d_in[2];
    const float* bz_f = (const float*)d_in[3];
    const float* Wh_f = (const float*)d_in[4];
    const float* bh_f = (const float*)d_in[5];
    const float* Wz_b = (const float*)d_in[6];
    const float* bz_b = (const float*)d_in[7];
    const float* Wh_b = (const float*)d_in[8];
    const float* bh_b = (const float*)d_in[9];

    const int T    = in_sizes[0] / D;            // 65536
    const int NCH  = T / BT;                     // 512
    const size_t TD = (size_t)T * D;
    const size_t WTE = 5 * 3 * 65536;

    // plan P: xb,qA,qB,xq (bf16) + wt + ab (u32) + aggA/aggB
    const size_t needP = 4 * TD * 2 + WTE * 2 + TD * 4 + (size_t)NCH * D * 4 * 2 + 4096;
    const bool planP = ws_size >= needP;

    dim3 blk(256);
    dim3 gGrid((unsigned)(NCH * 4));             // 2048
    dim3 pGrid((unsigned)(TD / 8 / 256));

    u16* xb = (u16*)d_ws;
    u16* qA = xb + TD;
    u16* qB = qA + TD;
    u16* xq = qB + TD;
    u16* wt = xq + TD;

    wtrans_kernel<<<dim3(5 * 3 * 65536 / 256), blk, 0, stream>>>(
        Wz_f, Wh_f, Wz_b, Wh_b, wt);
    prep0_kernel<<<pGrid, blk, 0, stream>>>(story, question, xb, qA, xq);

    const u16* qcur  = qA;
    u16*       qnext = qB;

    if (planP) {
        u32*   ab   = (u32*)(wt + WTE);
        float* aggA = (float*)(ab + TD);
        float* aggB = aggA + (size_t)NCH * D;
        float* hini = aggB;                      // alias (safe)

        for (int l = 0; l < 3; ++l) {
            const u16*   wtf = wt + (size_t)l * 3 * 65536;
            const float* bzf = bz_f + (size_t)l * D;
            const float* bhf = bh_f + (size_t)l * D;

            if (l == 2) {
                qrn_g5<1,0><<<gGrid, blk, 0, stream>>>(
                    xb, qcur, xq, wtf, bzf, bhf, aggA, aggB, nullptr);
                scan_p2_kernel<<<dim3(D), blk, 0, stream>>>(
                    aggA, aggB, hini, (float*)d_out, 1, NCH);
                break;
            }
            const u16*   wtb = wt + (size_t)(3 + l) * 3 * 65536;
            const float* bzb = bz_b + (size_t)l * D;
            const float* bhb = bh_b + (size_t)l * D;

            // forward
            qrn_g5<1,1><<<gGrid, blk, 0, stream>>>(
                xb, qcur, xq, wtf, bzf, bhf, aggA, aggB, ab);
            scan_p2_kernel<<<dim3(D), blk, 0, stream>>>(aggA, aggB, hini, nullptr, 1, NCH);
            replay_f<<<gGrid, blk, 0, stream>>>(ab, hini, qnext);

            // backward (reuses ab buffer)
            qrn_g5<0,1><<<gGrid, blk, 0, stream>>>(
                xb, qcur, xq, wtb, bzb, bhb, aggA, aggB, ab);
            scan_p2_kernel<<<dim3(D), blk, 0, stream>>>(aggA, aggB, hini, nullptr, 0, NCH);
            replay_b<<<gGrid, blk, 0, stream>>>(ab, hini, xb, qnext, xq);

            const u16* ts = qcur; qcur = qnext; qnext = (u16*)ts;
        }
    } else {
        // fallback: R4 tier-A schedule (9 GEMM evals)
        float* aggA = (float*)(wt + WTE);
        float* aggB = aggA + (size_t)NCH * D;
        float* hini = aggB;

        for (int l = 0; l < 3; ++l) {
            const u16*   wtf = wt + (size_t)l * 3 * 65536;
            const float* bzf = bz_f + (size_t)l * D;
            const float* bhf = bh_f + (size_t)l * D;

            if (l == 2) {
                qrn_gemm_fb<1,0><<<gGrid, blk, 0, stream>>>(
                    xb, qcur, xq, wtf, bzf, bhf, aggA, aggB, nullptr, nullptr);
                scan_p2_kernel<<<dim3(D), blk, 0, stream>>>(
                    aggA, aggB, hini, (float*)d_out, 1, NCH);
                break;
            }
            const u16*   wtb = wt + (size_t)(3 + l) * 3 * 65536;
            const float* bzb = bz_b + (size_t)l * D;
            const float* bhb = bh_b + (size_t)l * D;

            qrn_gemm_fb<1,0><<<gGrid, blk, 0, stream>>>(
                xb, qcur, xq, wtf, bzf, bhf, aggA, aggB, nullptr, nullptr);
            scan_p2_kernel<<<dim3(D), blk, 0, stream>>>(aggA, aggB, hini, nullptr, 1, NCH);
            qrn_gemm_fb<1,1><<<gGrid, blk, 0, stream>>>(
                xb, qcur, xq, wtf, bzf, bhf, nullptr, nullptr, hini, qnext);

            qrn_gemm_fb<0,0><<<gGrid, blk, 0, stream>>>(
                xb, qcur, xq, wtb, bzb, bhb, aggA, aggB, nullptr, nullptr);
            scan_p2_kernel<<<dim3(D), blk, 0, stream>>>(aggA, aggB, hini, nullptr, 0, NCH);
            qrn_gemm_fb<0,1><<<gGrid, blk, 0, stream>>>(
                xb, qcur, xq, wtb, bzb, bhb, nullptr, nullptr, hini, qnext);

            xq_upd_kernel<<<pGrid, blk, 0, stream>>>(xb, qnext, xq);

            const u16* ts = qcur; qcur = qnext; qnext = (u16*)ts;
        }
    }
}